// Round 4
// baseline (197.663 us; speedup 1.0000x reference)
//
#include <hip/hip_runtime.h>

// Problem constants (match reference)
#define B 16
#define C 128
#define N 16384
#define K 64

// Tiling
#define CT 16            // channels per block (16 -> 2048 blocks, 8/CU = 32 waves/CU)
#define NCH 16           // n-chunks per cloud
#define NB (N / NCH)     // 1024 points per block
#define NCT (C / CT)     // 8 channel tiles
#define LDSS 17          // K-row stride in LDS: bank = (17k+c)%32, 17 coprime to 32

#define ENC_NEG_INF 0x007FFFFFu  // enc(-inf)

__device__ __forceinline__ unsigned enc(float f) {
    unsigned u = __float_as_uint(f);
    return u ^ (unsigned)(((int)u >> 31) | (int)0x80000000);  // 3 VALU, branchless
}
__device__ __forceinline__ float dec(unsigned u) {
    unsigned v = (u & 0x80000000u) ? (u & 0x7FFFFFFFu) : ~u;
    return __uint_as_float(v);
}

// Partial tables in ws: part[b][ct][chunk][k][cl] (u32), 16*8*16*64*16*4B = 8 MB
__global__ __launch_bounds__(256, 8) void seg_scatter(const float* __restrict__ pf,
                                                      const int* __restrict__ ids,
                                                      unsigned* __restrict__ part) {
    __shared__ unsigned lds[K * LDSS];  // 1088 words = 4.3 KB
    const int tid   = threadIdx.x;
    const int chunk = blockIdx.x;
    const int ct    = blockIdx.y;
    const int b     = blockIdx.z;
    const int c0    = ct * CT;
    const int n0    = chunk * NB;

    for (int i = tid; i < K * LDSS; i += 256) lds[i] = ENC_NEG_INF;

    // 4 points per thread: one int4 of cluster ids, one float4 per channel.
    const int4 kk = reinterpret_cast<const int4*>(ids + b * N + n0)[tid];
    const int kx = kk.x * LDSS, ky = kk.y * LDSS, kz = kk.z * LDSS, kw = kk.w * LDSS;
    __syncthreads();

    const float* base = pf + ((size_t)b * C + c0) * N + n0;
    float4 cur = reinterpret_cast<const float4*>(base)[tid];
#pragma unroll
    for (int c = 0; c < CT; ++c) {
        float4 nxt = cur;
        if (c + 1 < CT)
            nxt = reinterpret_cast<const float4*>(base + (size_t)(c + 1) * N)[tid];
        atomicMax(&lds[kx + c], enc(cur.x));
        atomicMax(&lds[ky + c], enc(cur.y));
        atomicMax(&lds[kz + c], enc(cur.z));
        atomicMax(&lds[kw + c], enc(cur.w));
        cur = nxt;
    }
    __syncthreads();

    // Coalesced uint4 dump of the block-local K x CT table (no atomics).
    unsigned* dst = part + (((size_t)(b * NCT + ct) * NCH + chunk) * K) * CT;
    const int i4 = tid * 4;            // word index 0..1023
    const int k = i4 >> 4, cl = i4 & 15;
    const unsigned* src = &lds[k * LDSS + cl];
    uint4 v = make_uint4(src[0], src[1], src[2], src[3]);
    reinterpret_cast<uint4*>(dst)[tid] = v;
}

// Reduce the NCH partials and gather common cluster labels, 4 channels/thread.
__global__ __launch_bounds__(256) void seg_reduce(const unsigned* __restrict__ part,
                                                  const int* __restrict__ common,
                                                  float* __restrict__ out) {
    const int i = blockIdx.x * blockDim.x + threadIdx.x;  // over B*K*C/4 = 32768
    if (i >= B * K * C / 4) return;
    const int c0  = (i & 31) * 4;         // first channel of this quad (0..124)
    const int row = i >> 5;               // b*K + j
    const int cid = common[row];          // common cluster label
    const int b   = row >> 6;
    const int ct  = c0 >> 4;              // 0..7
    const int cl  = c0 & 15;              // 0,4,8,12

    const unsigned* p = part + (((size_t)(b * NCT + ct) * NCH) * K + cid) * CT + cl;
    uint4 m = make_uint4(ENC_NEG_INF, ENC_NEG_INF, ENC_NEG_INF, ENC_NEG_INF);
#pragma unroll
    for (int ch = 0; ch < NCH; ++ch) {
        uint4 v = *reinterpret_cast<const uint4*>(p + (size_t)ch * K * CT);
        m.x = max(m.x, v.x); m.y = max(m.y, v.y);
        m.z = max(m.z, v.z); m.w = max(m.w, v.w);
    }
    float4 o = make_float4(dec(m.x), dec(m.y), dec(m.z), dec(m.w));
    reinterpret_cast<float4*>(out)[i] = o;
}

extern "C" void kernel_launch(void* const* d_in, const int* in_sizes, int n_in,
                              void* d_out, int out_size, void* d_ws, size_t ws_size,
                              hipStream_t stream) {
    const float* pf     = (const float*)d_in[0];   // (B, C, N) f32
    const int*   ids    = (const int*)d_in[1];     // (B, N) i32
    const int*   common = (const int*)d_in[2];     // (B, K) i32
    float* out = (float*)d_out;                    // (B*K, C) f32
    unsigned* part = (unsigned*)d_ws;              // 8 MB partial tables

    dim3 grid(NCH, NCT, B);  // (16, 8, 16) = 2048 blocks
    seg_scatter<<<grid, 256, 0, stream>>>(pf, ids, part);

    const int rtotal = B * K * C / 4;  // 32768
    seg_reduce<<<(rtotal + 255) / 256, 256, 0, stream>>>(part, common, out);
}